// Round 1
// baseline (3347.918 us; speedup 1.0000x reference)
//
#include <hip/hip_runtime.h>
#include <math.h>

#define BATCH 4
#define SEQ   4096
#define EMB   1024
#define HDIM  64

// ---------------- QKV projection ----------------
// One block per (b,t) row. Stage x row (1024 f32 = 4KB) in LDS, then
// 192 threads each compute one output column of one of {Q,K,V}.
__global__ __launch_bounds__(256) void qkv_proj_kernel(
    const float* __restrict__ x,
    const float* __restrict__ Wq,
    const float* __restrict__ Wk,
    const float* __restrict__ Wv,
    float* __restrict__ q,
    float* __restrict__ k,
    float* __restrict__ v) {
  __shared__ float xs[EMB];
  const int row = blockIdx.x;                 // 0 .. BATCH*SEQ-1
  const float* xr = x + (size_t)row * EMB;
  for (int i = threadIdx.x; i < EMB; i += 256) xs[i] = xr[i];
  __syncthreads();
  const int t = threadIdx.x;
  if (t < 192) {
    const int m   = t >> 6;                   // 0=Q 1=K 2=V
    const int col = t & 63;
    const float* W = (m == 0) ? Wq : (m == 1) ? Wk : Wv;
    float acc = 0.f;
#pragma unroll 8
    for (int kk = 0; kk < EMB; ++kk)
      acc = fmaf(xs[kk], W[kk * HDIM + col], acc);
    if (m == 0) acc *= 0.03125f;              // fold C^-0.5 = 1/32 into q
    float* dst = (m == 0) ? q : (m == 1) ? k : v;
    dst[(size_t)row * HDIM + col] = acc;
  }
}

// ---------------- causal flash attention ----------------
// One 64-lane wave per query row; lane == head dim (HDIM==64).
// Online softmax; score reduce via 6-step shuffle butterfly.
__global__ __launch_bounds__(256) void attn_kernel(
    const float* __restrict__ q,
    const float* __restrict__ k,
    const float* __restrict__ v,
    float* __restrict__ out) {
  const int wid  = threadIdx.x >> 6;
  const int lane = threadIdx.x & 63;
  const int row  = blockIdx.x * 4 + wid;      // 0 .. BATCH*SEQ-1
  const int b  = row / SEQ;
  const int tq = row % SEQ;

  const float qv = q[(size_t)row * HDIM + lane];   // already scaled by 1/32
  const float* Kb = k + (size_t)b * SEQ * HDIM;
  const float* Vb = v + (size_t)b * SEQ * HDIM;

  float m = -INFINITY, l = 0.f, o = 0.f;
  for (int j = 0; j <= tq; ++j) {
    float s = qv * Kb[(size_t)j * HDIM + lane];
    s += __shfl_xor(s, 32);
    s += __shfl_xor(s, 16);
    s += __shfl_xor(s, 8);
    s += __shfl_xor(s, 4);
    s += __shfl_xor(s, 2);
    s += __shfl_xor(s, 1);
    const float mn   = fmaxf(m, s);
    const float corr = __expf(m - mn);        // first iter: exp(-inf)=0
    const float p    = __expf(s - mn);
    l = l * corr + p;
    o = o * corr + p * Vb[(size_t)j * HDIM + lane];
    m = mn;
  }
  out[(size_t)row * HDIM + lane] = o / l;
}

extern "C" void kernel_launch(void* const* d_in, const int* in_sizes, int n_in,
                              void* d_out, int out_size, void* d_ws, size_t ws_size,
                              hipStream_t stream) {
  const float* x  = (const float*)d_in[0];
  const float* Wq = (const float*)d_in[1];
  const float* Wk = (const float*)d_in[2];
  const float* Wv = (const float*)d_in[3];
  float* outp = (float*)d_out;

  const size_t rows = (size_t)BATCH * SEQ;          // 16384
  float* q = (float*)d_ws;                          // rows*64 f32
  float* k = q + rows * HDIM;
  float* v = k + rows * HDIM;                       // total 12 MB

  qkv_proj_kernel<<<dim3((unsigned)rows), dim3(256), 0, stream>>>(x, Wq, Wk, Wv, q, k, v);
  attn_kernel<<<dim3((unsigned)(rows / 4)), dim3(256), 0, stream>>>(q, k, v, outp);
}

// Round 2
// 492.000 us; speedup vs baseline: 6.8047x; 6.8047x over previous
//
#include <hip/hip_runtime.h>
#include <math.h>

#define BATCH 4
#define SEQ   4096
#define EMB   1024
#define HDIM  64

// ---------------- QKV projection ----------------
// 8 rows per block, 192 threads (3 waves: q/k/v). x rows staged transposed in
// LDS; each thread computes one output column for 8 rows, reusing each W value
// 8x (W L2 traffic /8 vs round-1). K written in per-64-key-tile transposed
// layout kt2[b][kb][d][j] so attention score loads are contiguous.
__global__ __launch_bounds__(192) void qkv_kernel(
    const float* __restrict__ x,
    const float* __restrict__ Wq,
    const float* __restrict__ Wk,
    const float* __restrict__ Wv,
    float* __restrict__ q,
    float* __restrict__ kt2,
    float* __restrict__ v) {
  __shared__ __align__(16) float xt[EMB][8];
  const int rb = blockIdx.x;
  const size_t row0 = (size_t)rb * 8;
  const float* xb = x + row0 * EMB;
  for (int i = threadIdx.x; i < EMB * 8; i += 192) {
    int r = i >> 10, kk = i & 1023;
    xt[kk][r] = xb[(size_t)r * EMB + kk];
  }
  __syncthreads();
  const int m3  = threadIdx.x >> 6;      // 0=Q 1=K 2=V
  const int col = threadIdx.x & 63;
  const float* W = (m3 == 0) ? Wq : (m3 == 1) ? Wk : Wv;
  float acc[8] = {0.f,0.f,0.f,0.f,0.f,0.f,0.f,0.f};
#pragma unroll 4
  for (int kk = 0; kk < EMB; ++kk) {
    float wv = W[kk * HDIM + col];
    float4 xa  = *(const float4*)&xt[kk][0];
    float4 xb4 = *(const float4*)&xt[kk][4];
    acc[0] = fmaf(xa.x,  wv, acc[0]);
    acc[1] = fmaf(xa.y,  wv, acc[1]);
    acc[2] = fmaf(xa.z,  wv, acc[2]);
    acc[3] = fmaf(xa.w,  wv, acc[3]);
    acc[4] = fmaf(xb4.x, wv, acc[4]);
    acc[5] = fmaf(xb4.y, wv, acc[5]);
    acc[6] = fmaf(xb4.z, wv, acc[6]);
    acc[7] = fmaf(xb4.w, wv, acc[7]);
  }
  if (m3 == 0) {
    for (int r = 0; r < 8; ++r) q[(row0 + r) * HDIM + col] = acc[r] * 0.03125f;
  } else if (m3 == 1) {
    const int b  = (int)(row0 >> 12);
    const int t0 = (int)(row0 & 4095);
    for (int r = 0; r < 8; ++r) {
      int t = t0 + r;
      kt2[(((size_t)b * 64 + (t >> 6)) * 64 + col) * 64 + (t & 63)] = acc[r];
    }
  } else {
    for (int r = 0; r < 8; ++r) v[(row0 + r) * HDIM + col] = acc[r];
  }
}

// ---------------- causal flash attention, lane-per-key blocked ----------------
// One wave = 4 query rows; inner step = 64 keys. lane=key for scores (K from
// kt2 tiles, coalesced), block max via 6-shuffle butterfly, p transposed
// through per-wave LDS for the PV accumulation (lane=dim, V coalesced).
// Complement block mapping (w vs 255-w per 256-chunk) balances causal work.
__global__ __launch_bounds__(256) void attn_kernel(
    const float* __restrict__ q,
    const float* __restrict__ kt2,
    const float* __restrict__ v,
    float* __restrict__ out) {
  __shared__ __align__(16) float qs[4][64][4];  // [wid][d][r]
  __shared__ __align__(16) float ps[4][64][4];  // [wid][key][r]
  const int wid  = threadIdx.x >> 6;
  const int lane = threadIdx.x & 63;
  const int bid   = blockIdx.x;
  const int batch = bid >> 8;
  int w = bid & 255;
  if (batch & 1) w = 255 - w;                   // complement pairing per CU
  const int tq0 = w * 16 + wid * 4;             // within-batch query base
  const size_t grow0 = (size_t)batch * SEQ + tq0;

  {  // stage q (already scaled by C^-0.5): qs[wid][d][r]
    const float* Qp = q + grow0 * HDIM;
    for (int r = 0; r < 4; ++r) qs[wid][lane][r] = Qp[(size_t)r * HDIM + lane];
  }
  __syncthreads();

  const float* Kb = kt2 + (size_t)batch * 64 * 64 * 64;
  const float* Vb = v   + (size_t)batch * SEQ * HDIM;

  float m[4], l[4], o[4];
#pragma unroll
  for (int r = 0; r < 4; ++r) { m[r] = -1e30f; l[r] = 0.f; o[r] = 0.f; }

  const int nb = ((tq0 + 3) >> 6) + 1;
  for (int kb = 0; kb < nb; ++kb) {
    const int j0  = kb << 6;
    const int key = j0 + lane;
    // ---- scores: s[r] = q[r] . K[key] ----
    const float* kp = Kb + (size_t)kb * 64 * 64 + lane;
    float s0 = 0.f, s1 = 0.f, s2 = 0.f, s3 = 0.f;
#pragma unroll 8
    for (int d0 = 0; d0 < 64; ++d0) {
      float kd = kp[d0 * 64];
      float4 q4 = *(const float4*)&qs[wid][d0][0];
      s0 = fmaf(q4.x, kd, s0);
      s1 = fmaf(q4.y, kd, s1);
      s2 = fmaf(q4.z, kd, s2);
      s3 = fmaf(q4.w, kd, s3);
    }
    // ---- causal mask ----
    s0 = (key <= tq0 + 0) ? s0 : -INFINITY;
    s1 = (key <= tq0 + 1) ? s1 : -INFINITY;
    s2 = (key <= tq0 + 2) ? s2 : -INFINITY;
    s3 = (key <= tq0 + 3) ? s3 : -INFINITY;
    // ---- block max (butterfly) ----
    float b0 = s0, b1 = s1, b2 = s2, b3 = s3;
#pragma unroll
    for (int off = 32; off; off >>= 1) {
      b0 = fmaxf(b0, __shfl_xor(b0, off));
      b1 = fmaxf(b1, __shfl_xor(b1, off));
      b2 = fmaxf(b2, __shfl_xor(b2, off));
      b3 = fmaxf(b3, __shfl_xor(b3, off));
    }
    // ---- online softmax update (wave-uniform corr) ----
    float p0, p1, p2, p3;
    {
      float nm = fmaxf(m[0], b0); float c = __expf(m[0] - nm);
      p0 = __expf(s0 - nm); l[0] = l[0] * c + p0; o[0] *= c; m[0] = nm;
    }
    {
      float nm = fmaxf(m[1], b1); float c = __expf(m[1] - nm);
      p1 = __expf(s1 - nm); l[1] = l[1] * c + p1; o[1] *= c; m[1] = nm;
    }
    {
      float nm = fmaxf(m[2], b2); float c = __expf(m[2] - nm);
      p2 = __expf(s2 - nm); l[2] = l[2] * c + p2; o[2] *= c; m[2] = nm;
    }
    {
      float nm = fmaxf(m[3], b3); float c = __expf(m[3] - nm);
      p3 = __expf(s3 - nm); l[3] = l[3] * c + p3; o[3] *= c; m[3] = nm;
    }
    // ---- p transpose via per-wave LDS ----
    float4 pv = {p0, p1, p2, p3};
    *(float4*)&ps[wid][lane][0] = pv;
    asm volatile("s_waitcnt lgkmcnt(0)" ::: "memory");
    // ---- PV: lane=dim, V coalesced, p broadcast ----
    const float* vp = Vb + (size_t)j0 * HDIM + lane;
#pragma unroll 8
    for (int j = 0; j < 64; ++j) {
      float vr = vp[j * 64];
      float4 pj = *(const float4*)&ps[wid][j][0];
      o[0] = fmaf(pj.x, vr, o[0]);
      o[1] = fmaf(pj.y, vr, o[1]);
      o[2] = fmaf(pj.z, vr, o[2]);
      o[3] = fmaf(pj.w, vr, o[3]);
    }
  }
  // ---- final l reduce + store ----
#pragma unroll
  for (int off = 32; off; off >>= 1) {
    l[0] += __shfl_xor(l[0], off);
    l[1] += __shfl_xor(l[1], off);
    l[2] += __shfl_xor(l[2], off);
    l[3] += __shfl_xor(l[3], off);
  }
  for (int r = 0; r < 4; ++r)
    out[(grow0 + r) * HDIM + lane] = o[r] / l[r];
}

extern "C" void kernel_launch(void* const* d_in, const int* in_sizes, int n_in,
                              void* d_out, int out_size, void* d_ws, size_t ws_size,
                              hipStream_t stream) {
  const float* x  = (const float*)d_in[0];
  const float* Wq = (const float*)d_in[1];
  const float* Wk = (const float*)d_in[2];
  const float* Wv = (const float*)d_in[3];
  float* outp = (float*)d_out;

  const size_t rows = (size_t)BATCH * SEQ;  // 16384
  float* q   = (float*)d_ws;                // rows*64
  float* kt2 = q + rows * HDIM;             // 4*64*64*64 == rows*64
  float* v   = kt2 + rows * HDIM;

  qkv_kernel<<<dim3((unsigned)(rows / 8)), dim3(192), 0, stream>>>(x, Wq, Wk, Wv, q, kt2, v);
  attn_kernel<<<dim3((unsigned)(rows / 16)), dim3(256), 0, stream>>>(q, kt2, v, outp);
}

// Round 3
// 223.590 us; speedup vs baseline: 14.9735x; 2.2005x over previous
//
#include <hip/hip_runtime.h>
#include <math.h>

#define BATCH 4
#define SEQ   4096
#define EMB   1024
#define HDIM  64

typedef __attribute__((ext_vector_type(8))) short bf16x8;
typedef __attribute__((ext_vector_type(4))) float f32x4;

#define MFMA16(a, b, c) __builtin_amdgcn_mfma_f32_16x16x32_bf16(a, b, c, 0, 0, 0)

__device__ __forceinline__ unsigned short f2bf(float f) {
  unsigned int u = __float_as_uint(f);
  u = (u + 0x7FFFu + ((u >> 16) & 1u)) >> 16;   // RNE
  return (unsigned short)u;
}

// ---------------- QKV projection (fp32 compute, bf16 outputs) ----------------
// 8 rows/block, 192 threads. q_bf,k_bf row-major [row][d]; V stored transposed
// per 64-key tile: vt[b][kb][d][j] so attention PV A-fragments are contiguous.
__global__ __launch_bounds__(192) void qkv_kernel(
    const float* __restrict__ x, const float* __restrict__ Wq,
    const float* __restrict__ Wk, const float* __restrict__ Wv,
    unsigned short* __restrict__ qb, unsigned short* __restrict__ kb,
    unsigned short* __restrict__ vt) {
  __shared__ __align__(16) float xt[EMB][8];
  const int rb = blockIdx.x;
  const size_t row0 = (size_t)rb * 8;
  const float* xb = x + row0 * EMB;
  for (int i = threadIdx.x; i < EMB * 8; i += 192) {
    int r = i >> 10, kk = i & 1023;
    xt[kk][r] = xb[(size_t)r * EMB + kk];
  }
  __syncthreads();
  const int m3  = threadIdx.x >> 6;
  const int col = threadIdx.x & 63;
  const float* W = (m3 == 0) ? Wq : (m3 == 1) ? Wk : Wv;
  float acc[8] = {0.f,0.f,0.f,0.f,0.f,0.f,0.f,0.f};
#pragma unroll 4
  for (int kk = 0; kk < EMB; ++kk) {
    float wv = W[kk * HDIM + col];
    float4 xa  = *(const float4*)&xt[kk][0];
    float4 xb4 = *(const float4*)&xt[kk][4];
    acc[0] = fmaf(xa.x,  wv, acc[0]);
    acc[1] = fmaf(xa.y,  wv, acc[1]);
    acc[2] = fmaf(xa.z,  wv, acc[2]);
    acc[3] = fmaf(xa.w,  wv, acc[3]);
    acc[4] = fmaf(xb4.x, wv, acc[4]);
    acc[5] = fmaf(xb4.y, wv, acc[5]);
    acc[6] = fmaf(xb4.z, wv, acc[6]);
    acc[7] = fmaf(xb4.w, wv, acc[7]);
  }
  if (m3 == 0) {
    for (int r = 0; r < 8; ++r) qb[(row0 + r) * HDIM + col] = f2bf(acc[r] * 0.03125f);
  } else if (m3 == 1) {
    for (int r = 0; r < 8; ++r) kb[(row0 + r) * HDIM + col] = f2bf(acc[r]);
  } else {
    const int b  = (int)(row0 >> 12);
    const int t0 = (int)(row0 & 4095);
    for (int r = 0; r < 8; ++r) {
      int t = t0 + r;
      vt[(((size_t)b * 64 + (t >> 6)) * 64 + col) * 64 + (t & 63)] = f2bf(acc[r]);
    }
  }
}

// ---------------- MFMA flash attention ----------------
// Block = 4 waves sharing 16 queries; wave wid takes key tiles kb=wid,wid+4,...
// (flash split-K), merged via LDS at the end. Swapped S^T = mfma(K,Q):
// C/D map (verified): col=lane&15 (query), row=(lane>>4)*4+reg (key).
// A/B operands: row|col = lane&15, k spans (lane>>4, e) — both operands of each
// MFMA use the same (g,e)->k map, so HW k-order cancels.
__global__ __launch_bounds__(256) void attn_kernel(
    const unsigned short* __restrict__ qb, const unsigned short* __restrict__ kbm,
    const unsigned short* __restrict__ vt, float* __restrict__ out) {
  __shared__ float msh[4][16], lsh[4][16];
  __shared__ float osh[4][64][17];
  const int wid  = threadIdx.x >> 6;
  const int lane = threadIdx.x & 63;
  const int g = lane >> 4, p = lane & 15;
  const int bid = blockIdx.x, batch = bid >> 8;
  int w = bid & 255;
  if (batch & 1) w = 255 - w;                 // causal load balance
  const int tq0 = w * 16;
  const size_t grow0 = (size_t)batch * SEQ + tq0;
  const int kbd = w >> 2;                     // diagonal 64-key tile

  // Q as B-operand fragments: col=query p, k=dim 32h+8g+e
  const unsigned short* qrow = qb + (grow0 + p) * HDIM;
  const bf16x8 qf0 = *(const bf16x8*)(qrow + 8 * g);
  const bf16x8 qf1 = *(const bf16x8*)(qrow + 32 + 8 * g);

  const unsigned short* kbase = kbm + (size_t)batch * SEQ * HDIM;
  const unsigned short* vbase = vt  + (size_t)batch * SEQ * HDIM;

  const int srcA = (g & 1) * 32 + p;          // source lane for e=0..3
  const int srcB = srcA + 16;                 // source lane for e=4..7
  const bool hi = (g >> 1) != 0;

  float m = -1e30f, l = 0.f;
  f32x4 o[4];
#pragma unroll
  for (int mi = 0; mi < 4; ++mi) o[mi] = (f32x4){0.f, 0.f, 0.f, 0.f};

  for (int kt = wid; kt <= kbd; kt += 4) {
    // ---- S^T = K . Q^T over 64 keys ----
    const unsigned short* kp = kbase + ((size_t)(kt * 64 + p)) * 64 + 8 * g;
    f32x4 s[4];
#pragma unroll
    for (int t = 0; t < 4; ++t) {
      bf16x8 a0 = *(const bf16x8*)(kp + t * 1024);
      bf16x8 a1 = *(const bf16x8*)(kp + t * 1024 + 32);
      f32x4 acc = (f32x4){0.f, 0.f, 0.f, 0.f};
      acc = MFMA16(a0, qf0, acc);
      acc = MFMA16(a1, qf1, acc);
      s[t] = acc;
    }
    // ---- causal mask (diag tile only): key = kt*64+16t+4g+r vs query tq0+p
    if (kt == kbd) {
#pragma unroll
      for (int t = 0; t < 4; ++t)
#pragma unroll
        for (int r = 0; r < 4; ++r) {
          int key = kt * 64 + 16 * t + 4 * g + r;
          if (key > tq0 + p) s[t][r] = -1e30f;
        }
    }
    // ---- online softmax (per lane: 16 of 64 keys for query p) ----
    float tm = -1e30f;
#pragma unroll
    for (int t = 0; t < 4; ++t)
#pragma unroll
      for (int r = 0; r < 4; ++r) tm = fmaxf(tm, s[t][r]);
    tm = fmaxf(tm, __shfl_xor(tm, 16));
    tm = fmaxf(tm, __shfl_xor(tm, 32));
    const float mn = fmaxf(m, tm);
    const float corr = __expf(m - mn);
    m = mn;
    float psum = 0.f;
#pragma unroll
    for (int t = 0; t < 4; ++t)
#pragma unroll
      for (int r = 0; r < 4; ++r) {
        float pv = __expf(s[t][r] - mn);
        s[t][r] = pv;
        psum += pv;
      }
    l = l * corr + psum;
#pragma unroll
    for (int mi = 0; mi < 4; ++mi) o[mi] *= corr;
    // ---- P^T -> B-operand fragments (keys k=32h+8g+e) ----
    bf16x8 b0, b1;
#pragma unroll
    for (int r = 0; r < 4; ++r) {
      float v0 = __shfl(s[0][r], srcA), v1 = __shfl(s[1][r], srcA);
      float v2 = __shfl(s[0][r], srcB), v3 = __shfl(s[1][r], srcB);
      b0[r]     = (short)f2bf(hi ? v1 : v0);
      b0[4 + r] = (short)f2bf(hi ? v3 : v2);
      float u0 = __shfl(s[2][r], srcA), u1 = __shfl(s[3][r], srcA);
      float u2 = __shfl(s[2][r], srcB), u3 = __shfl(s[3][r], srcB);
      b1[r]     = (short)f2bf(hi ? u1 : u0);
      b1[4 + r] = (short)f2bf(hi ? u3 : u2);
    }
    // ---- O^T += V^T . P^T ----
    const unsigned short* vp = vbase + (size_t)kt * 4096 + p * 64 + 8 * g;
#pragma unroll
    for (int mi = 0; mi < 4; ++mi) {
      bf16x8 va0 = *(const bf16x8*)(vp + mi * 1024);
      bf16x8 va1 = *(const bf16x8*)(vp + mi * 1024 + 32);
      o[mi] = MFMA16(va0, b0, o[mi]);
      o[mi] = MFMA16(va1, b1, o[mi]);
    }
  }

  // ---- merge the 4 key-split partials ----
  l += __shfl_xor(l, 16);
  l += __shfl_xor(l, 32);
  if (g == 0) { msh[wid][p] = m; lsh[wid][p] = l; }
#pragma unroll
  for (int mi = 0; mi < 4; ++mi)
#pragma unroll
    for (int r = 0; r < 4; ++r) osh[wid][16 * mi + 4 * g + r][p] = o[mi][r];
  __syncthreads();

  const int q  = threadIdx.x & 15;
  const int db = threadIdx.x >> 4;            // 0..15 -> dims 4*db..4*db+3
  float mm = fmaxf(fmaxf(msh[0][q], msh[1][q]), fmaxf(msh[2][q], msh[3][q]));
  float L = 0.f, a0 = 0.f, a1 = 0.f, a2 = 0.f, a3 = 0.f;
#pragma unroll
  for (int wv = 0; wv < 4; ++wv) {
    float sc = __expf(msh[wv][q] - mm);
    L  += lsh[wv][q] * sc;
    a0 += osh[wv][4 * db + 0][q] * sc;
    a1 += osh[wv][4 * db + 1][q] * sc;
    a2 += osh[wv][4 * db + 2][q] * sc;
    a3 += osh[wv][4 * db + 3][q] * sc;
  }
  const float inv = 1.f / L;
  float* op = out + (grow0 + q) * HDIM + 4 * db;
  op[0] = a0 * inv; op[1] = a1 * inv; op[2] = a2 * inv; op[3] = a3 * inv;
}

extern "C" void kernel_launch(void* const* d_in, const int* in_sizes, int n_in,
                              void* d_out, int out_size, void* d_ws, size_t ws_size,
                              hipStream_t stream) {
  const float* x  = (const float*)d_in[0];
  const float* Wq = (const float*)d_in[1];
  const float* Wk = (const float*)d_in[2];
  const float* Wv = (const float*)d_in[3];
  float* outp = (float*)d_out;

  const size_t rows = (size_t)BATCH * SEQ;    // 16384
  unsigned short* qbf = (unsigned short*)d_ws;
  unsigned short* kbf = qbf + rows * HDIM;
  unsigned short* vtb = kbf + rows * HDIM;    // 6 MB total

  qkv_kernel<<<dim3((unsigned)(rows / 8)), dim3(192), 0, stream>>>(x, Wq, Wk, Wv, qbf, kbf, vtb);
  attn_kernel<<<dim3((unsigned)(rows / 16)), dim3(256), 0, stream>>>(qbf, kbf, vtb, outp);
}

// Round 4
// 89.939 us; speedup vs baseline: 37.2242x; 2.4860x over previous
//
#include <hip/hip_runtime.h>
#include <math.h>

#define BATCH 4
#define SEQ   4096
#define EMB   1024
#define HDIM  64

typedef __attribute__((ext_vector_type(8))) short bf16x8;
typedef __attribute__((ext_vector_type(4))) float f32x4;

#define MFMA16(a, b, c) __builtin_amdgcn_mfma_f32_16x16x32_bf16(a, b, c, 0, 0, 0)

__device__ __forceinline__ unsigned short f2bf(float f) {
  unsigned int u = __float_as_uint(f);
  u = (u + 0x7FFFu + ((u >> 16) & 1u)) >> 16;   // RNE
  return (unsigned short)u;
}

// ---------------- W pre-transpose: W[1024][64] f32 x3 -> Wt[192][1024] bf16 --
__global__ __launch_bounds__(256) void wt_kernel(
    const float* __restrict__ Wq, const float* __restrict__ Wk,
    const float* __restrict__ Wv, unsigned short* __restrict__ wt) {
  __shared__ float tile[64][65];
  const int bid = blockIdx.x;           // 48 = 3 matrices x 16 k-tiles
  const int m = bid >> 4, kt = bid & 15;
  const float* W = (m == 0) ? Wq : (m == 1) ? Wk : Wv;
  const int tid = threadIdx.x;
  {
    const int r = tid >> 2, c4 = tid & 3;          // k-row, 16-col group
    const float* src = W + (size_t)(kt * 64 + r) * 64 + c4 * 16;
#pragma unroll
    for (int j = 0; j < 4; ++j) {
      float4 a = *(const float4*)(src + j * 4);
      tile[r][c4 * 16 + j * 4 + 0] = a.x;
      tile[r][c4 * 16 + j * 4 + 1] = a.y;
      tile[r][c4 * 16 + j * 4 + 2] = a.z;
      tile[r][c4 * 16 + j * 4 + 3] = a.w;
    }
  }
  __syncthreads();
  {
    const int col = tid >> 2, kq = tid & 3;        // out col, 16-k group
    unsigned short o[16];
#pragma unroll
    for (int j = 0; j < 16; ++j) o[j] = f2bf(tile[kq * 16 + j][col]);
    unsigned short* dst = wt + (size_t)(m * 64 + col) * 1024 + kt * 64 + kq * 16;
    *(bf16x8*)(dst)     = *(bf16x8*)&o[0];
    *(bf16x8*)(dst + 8) = *(bf16x8*)&o[8];
  }
}

// ---------------- QKV projection via MFMA ----------------
// 512 blocks (2/CU): 32-row M-tile x all 192 cols. K chunks of 64, bf16 in
// XOR-swizzled LDS; T14 reg-prefetch of next chunk. Wave w owns cols 48w..48w+47.
__global__ __launch_bounds__(256) void qkv_mfma_kernel(
    const float* __restrict__ x, const unsigned short* __restrict__ wt,
    unsigned short* __restrict__ qb, unsigned short* __restrict__ kb,
    unsigned short* __restrict__ vt) {
  __shared__ __align__(16) unsigned short xs[32 * 64];   // [row][k] swizzled
  __shared__ __align__(16) unsigned short ws[192 * 64];  // [col][k] swizzled
  const int tid  = threadIdx.x;
  const int lane = tid & 63, wid = tid >> 6;
  const int g = lane >> 4, p = lane & 15;
  const size_t row0 = (size_t)blockIdx.x * 32;

  // staging maps
  const int sr = tid >> 3, sc = tid & 7;                 // x: row, 8-k group
  const float* xp = x + (row0 + sr) * EMB + sc * 8;

  f32x4 acc[2][3];
#pragma unroll
  for (int rt = 0; rt < 2; ++rt)
#pragma unroll
    for (int ct = 0; ct < 3; ++ct) acc[rt][ct] = (f32x4){0.f, 0.f, 0.f, 0.f};

  float4 rx[2];
  bf16x8 rw[6];
  // prologue: load chunk 0
#pragma unroll
  for (int j = 0; j < 2; ++j) rx[j] = *(const float4*)(xp + j * 4);
#pragma unroll
  for (int it = 0; it < 6; ++it) {
    int i = tid + it * 256, col = i >> 3, cc = i & 7;
    rw[it] = *(const bf16x8*)(wt + (size_t)col * 1024 + cc * 8);
  }

  for (int kc = 0; kc < 16; ++kc) {
    __syncthreads();                       // previous chunk's reads done
    // ds_write staged regs (swizzled)
#pragma unroll
    for (int j = 0; j < 2; ++j) {
      ushort4 h;
      h.x = f2bf(rx[j].x); h.y = f2bf(rx[j].y);
      h.z = f2bf(rx[j].z); h.w = f2bf(rx[j].w);
      *(ushort4*)((char*)xs + ((sr * 128 + sc * 16 + j * 8) ^ ((sr & 7) << 4))) = h;
    }
#pragma unroll
    for (int it = 0; it < 6; ++it) {
      int i = tid + it * 256, col = i >> 3, cc = i & 7;
      *(bf16x8*)((char*)ws + ((col * 128 + cc * 16) ^ ((col & 7) << 4))) = rw[it];
    }
    // prefetch next chunk (completes under MFMA phase)
    if (kc < 15) {
      const float* xpn = xp + (kc + 1) * 64;
#pragma unroll
      for (int j = 0; j < 2; ++j) rx[j] = *(const float4*)(xpn + j * 4);
#pragma unroll
      for (int it = 0; it < 6; ++it) {
        int i = tid + it * 256, col = i >> 3, cc = i & 7;
        rw[it] = *(const bf16x8*)(wt + (size_t)col * 1024 + (kc + 1) * 64 + cc * 8);
      }
    }
    __syncthreads();
    // compute: 2 k-steps of 32
#pragma unroll
    for (int ks = 0; ks < 2; ++ks) {
      bf16x8 af[2];
#pragma unroll
      for (int rt = 0; rt < 2; ++rt) {
        int row = rt * 16 + p;
        af[rt] = *(const bf16x8*)((char*)xs +
                 ((row * 128 + ks * 64 + g * 16) ^ ((row & 7) << 4)));
      }
#pragma unroll
      for (int ct = 0; ct < 3; ++ct) {
        int col = wid * 48 + ct * 16 + p;
        bf16x8 bfr = *(const bf16x8*)((char*)ws +
                     ((col * 128 + ks * 64 + g * 16) ^ ((col & 7) << 4)));
#pragma unroll
        for (int rt = 0; rt < 2; ++rt)
          acc[rt][ct] = MFMA16(af[rt], bfr, acc[rt][ct]);
      }
    }
  }

  // epilogue: D[row=rt*16+4g+r][col=16ct'+p]
  const int b     = (int)(row0 >> 12);
  const int tbase = (int)(row0 & 4095);
  unsigned short* vtb = vt + (((size_t)b * 64 + (tbase >> 6)) * 64) * 64 + (tbase & 63);
#pragma unroll
  for (int rt = 0; rt < 2; ++rt)
#pragma unroll
    for (int ct = 0; ct < 3; ++ct) {
      const int c0  = wid * 48 + ct * 16;
      const int mtx = c0 >> 6;
      const int col = (c0 & 63) + p;
#pragma unroll
      for (int r = 0; r < 4; ++r) {
        const int row = rt * 16 + 4 * g + r;
        const float vf = acc[rt][ct][r];
        if (mtx == 0)      qb[(row0 + row) * HDIM + col] = f2bf(vf * 0.03125f);
        else if (mtx == 1) kb[(row0 + row) * HDIM + col] = f2bf(vf);
        else               vtb[(size_t)col * 64 + row]   = f2bf(vf);
      }
    }
}

// ---------------- MFMA flash attention (unchanged from round 3) -------------
__global__ __launch_bounds__(256) void attn_kernel(
    const unsigned short* __restrict__ qb, const unsigned short* __restrict__ kbm,
    const unsigned short* __restrict__ vt, float* __restrict__ out) {
  __shared__ float msh[4][16], lsh[4][16];
  __shared__ float osh[4][64][17];
  const int wid  = threadIdx.x >> 6;
  const int lane = threadIdx.x & 63;
  const int g = lane >> 4, p = lane & 15;
  const int bid = blockIdx.x, batch = bid >> 8;
  int w = bid & 255;
  if (batch & 1) w = 255 - w;
  const int tq0 = w * 16;
  const size_t grow0 = (size_t)batch * SEQ + tq0;
  const int kbd = w >> 2;

  const unsigned short* qrow = qb + (grow0 + p) * HDIM;
  const bf16x8 qf0 = *(const bf16x8*)(qrow + 8 * g);
  const bf16x8 qf1 = *(const bf16x8*)(qrow + 32 + 8 * g);

  const unsigned short* kbase = kbm + (size_t)batch * SEQ * HDIM;
  const unsigned short* vbase = vt  + (size_t)batch * SEQ * HDIM;

  const int srcA = (g & 1) * 32 + p;
  const int srcB = srcA + 16;
  const bool hi = (g >> 1) != 0;

  float m = -1e30f, l = 0.f;
  f32x4 o[4];
#pragma unroll
  for (int mi = 0; mi < 4; ++mi) o[mi] = (f32x4){0.f, 0.f, 0.f, 0.f};

  for (int kt = wid; kt <= kbd; kt += 4) {
    const unsigned short* kp = kbase + ((size_t)(kt * 64 + p)) * 64 + 8 * g;
    f32x4 s[4];
#pragma unroll
    for (int t = 0; t < 4; ++t) {
      bf16x8 a0 = *(const bf16x8*)(kp + t * 1024);
      bf16x8 a1 = *(const bf16x8*)(kp + t * 1024 + 32);
      f32x4 acc = (f32x4){0.f, 0.f, 0.f, 0.f};
      acc = MFMA16(a0, qf0, acc);
      acc = MFMA16(a1, qf1, acc);
      s[t] = acc;
    }
    if (kt == kbd) {
#pragma unroll
      for (int t = 0; t < 4; ++t)
#pragma unroll
        for (int r = 0; r < 4; ++r) {
          int key = kt * 64 + 16 * t + 4 * g + r;
          if (key > tq0 + p) s[t][r] = -1e30f;
        }
    }
    float tm = -1e30f;
#pragma unroll
    for (int t = 0; t < 4; ++t)
#pragma unroll
      for (int r = 0; r < 4; ++r) tm = fmaxf(tm, s[t][r]);
    tm = fmaxf(tm, __shfl_xor(tm, 16));
    tm = fmaxf(tm, __shfl_xor(tm, 32));
    const float mn = fmaxf(m, tm);
    const float corr = __expf(m - mn);
    m = mn;
    float psum = 0.f;
#pragma unroll
    for (int t = 0; t < 4; ++t)
#pragma unroll
      for (int r = 0; r < 4; ++r) {
        float pv = __expf(s[t][r] - mn);
        s[t][r] = pv;
        psum += pv;
      }
    l = l * corr + psum;
#pragma unroll
    for (int mi = 0; mi < 4; ++mi) o[mi] *= corr;
    bf16x8 b0, b1;
#pragma unroll
    for (int r = 0; r < 4; ++r) {
      float v0 = __shfl(s[0][r], srcA), v1 = __shfl(s[1][r], srcA);
      float v2 = __shfl(s[0][r], srcB), v3 = __shfl(s[1][r], srcB);
      b0[r]     = (short)f2bf(hi ? v1 : v0);
      b0[4 + r] = (short)f2bf(hi ? v3 : v2);
      float u0 = __shfl(s[2][r], srcA), u1 = __shfl(s[3][r], srcA);
      float u2 = __shfl(s[2][r], srcB), u3 = __shfl(s[3][r], srcB);
      b1[r]     = (short)f2bf(hi ? u1 : u0);
      b1[4 + r] = (short)f2bf(hi ? u3 : u2);
    }
    const unsigned short* vp = vbase + (size_t)kt * 4096 + p * 64 + 8 * g;
#pragma unroll
    for (int mi = 0; mi < 4; ++mi) {
      bf16x8 va0 = *(const bf16x8*)(vp + mi * 1024);
      bf16x8 va1 = *(const bf16x8*)(vp + mi * 1024 + 32);
      o[mi] = MFMA16(va0, b0, o[mi]);
      o[mi] = MFMA16(va1, b1, o[mi]);
    }
  }

  l += __shfl_xor(l, 16);
  l += __shfl_xor(l, 32);
  if (g == 0) { msh[wid][p] = m; lsh[wid][p] = l; }
#pragma unroll
  for (int mi = 0; mi < 4; ++mi)
#pragma unroll
    for (int r = 0; r < 4; ++r) osh[wid][16 * mi + 4 * g + r][p] = o[mi][r];
  __syncthreads();

  const int q  = threadIdx.x & 15;
  const int db = threadIdx.x >> 4;
  float mm = fmaxf(fmaxf(msh[0][q], msh[1][q]), fmaxf(msh[2][q], msh[3][q]));
  float L = 0.f, a0 = 0.f, a1 = 0.f, a2 = 0.f, a3 = 0.f;
#pragma unroll
  for (int wv = 0; wv < 4; ++wv) {
    float sc = __expf(msh[wv][q] - mm);
    L  += lsh[wv][q] * sc;
    a0 += osh[wv][4 * db + 0][q] * sc;
    a1 += osh[wv][4 * db + 1][q] * sc;
    a2 += osh[wv][4 * db + 2][q] * sc;
    a3 += osh[wv][4 * db + 3][q] * sc;
  }
  const float inv = 1.f / L;
  float* op = out + (grow0 + q) * HDIM + 4 * db;
  op[0] = a0 * inv; op[1] = a1 * inv; op[2] = a2 * inv; op[3] = a3 * inv;
}

extern "C" void kernel_launch(void* const* d_in, const int* in_sizes, int n_in,
                              void* d_out, int out_size, void* d_ws, size_t ws_size,
                              hipStream_t stream) {
  const float* x  = (const float*)d_in[0];
  const float* Wq = (const float*)d_in[1];
  const float* Wk = (const float*)d_in[2];
  const float* Wv = (const float*)d_in[3];
  float* outp = (float*)d_out;

  const size_t rows = (size_t)BATCH * SEQ;        // 16384
  unsigned short* qbf = (unsigned short*)d_ws;
  unsigned short* kbf = qbf + rows * HDIM;
  unsigned short* vtb = kbf + rows * HDIM;
  unsigned short* wt  = vtb + rows * HDIM;        // 192*1024 bf16

  wt_kernel<<<dim3(48), dim3(256), 0, stream>>>(Wq, Wk, Wv, wt);
  qkv_mfma_kernel<<<dim3((unsigned)(rows / 32)), dim3(256), 0, stream>>>(x, wt, qbf, kbf, vtb);
  attn_kernel<<<dim3((unsigned)(rows / 16)), dim3(256), 0, stream>>>(qbf, kbf, vtb, outp);
}